// Round 3
// baseline (492.468 us; speedup 1.0000x reference)
//
#include <hip/hip_runtime.h>

#define N_NODESC 20000
#define N_EDGESC 1280000
#define CH 256
#define CH4 64

// ---- workspace layout (bytes, all 16B-aligned) ----
constexpr size_t OFF_DEG      = 0;                      // int[20000]
constexpr size_t OFF_ROWSTART = 81920;                  // int[20001]
constexpr size_t OFF_CURSOR   = 163840;                 // int[20000]
constexpr size_t OFF_INVDEG   = 245760;                 // float[20000]
constexpr size_t OFF_ACCUM    = 327680;                 // float[1]
constexpr size_t OFF_BSUM     = 327696;                 // int[128]
constexpr size_t OFF_BOFF     = 328208;                 // int[128]
constexpr size_t OFF_CSR      = 331776;                 // int[1280000]
constexpr size_t OFF_MEAN     = OFF_CSR  + 5120000;     // float[20000*256]
constexpr size_t OFF_S1       = OFF_MEAN + 20480000;    // float[20000]
constexpr size_t OFF_T1       = OFF_S1   + 80000;       // float[20000]

static __device__ __forceinline__ float4 f4add(float4 a, float4 b) {
    return make_float4(a.x + b.x, a.y + b.y, a.z + b.z, a.w + b.w);
}

__global__ void k_zero(int* __restrict__ deg, float* __restrict__ s1,
                       float* __restrict__ t1, float* __restrict__ accum) {
    int i = blockIdx.x * blockDim.x + threadIdx.x;
    if (i < N_NODESC) { deg[i] = 0; s1[i] = 0.0f; t1[i] = 0.0f; }
    if (i == 0) accum[0] = 0.0f;
}

__global__ void k_count(const int* __restrict__ ei, int* __restrict__ deg) {
    int e = blockIdx.x * blockDim.x + threadIdx.x;
    if (e < N_EDGESC) atomicAdd(&deg[ei[N_EDGESC + e]], 1);
}

// --- 3-phase scan: block sums -> scan of block sums -> per-block scan ---
__global__ void __launch_bounds__(256) k_scan1(const int* __restrict__ deg,
                                               int* __restrict__ bsum) {
    __shared__ int sm[4];
    int i = blockIdx.x * 256 + threadIdx.x;
    int v = (i < N_NODESC) ? deg[i] : 0;
    #pragma unroll
    for (int off = 32; off > 0; off >>= 1) v += __shfl_down(v, off);
    if ((threadIdx.x & 63) == 0) sm[threadIdx.x >> 6] = v;
    __syncthreads();
    if (threadIdx.x == 0) bsum[blockIdx.x] = sm[0] + sm[1] + sm[2] + sm[3];
}

__global__ void k_scan2(const int* __restrict__ bsum, int* __restrict__ boff,
                        int* __restrict__ row_start) {
    __shared__ int sm[128];
    int t = threadIdx.x;
    int v = (t < 79) ? bsum[t] : 0;
    sm[t] = v;
    __syncthreads();
    for (int off = 1; off < 128; off <<= 1) {
        int add = (t >= off) ? sm[t - off] : 0;
        __syncthreads();
        sm[t] += add;
        __syncthreads();
    }
    if (t < 79) boff[t] = sm[t] - v;
    if (t == 0) row_start[N_NODESC] = sm[127];
}

__global__ void __launch_bounds__(256) k_scan3(
        const int* __restrict__ deg, const int* __restrict__ boff,
        int* __restrict__ row_start, int* __restrict__ cursor,
        float* __restrict__ inv_deg) {
    __shared__ int wsum[4];
    int i = blockIdx.x * 256 + threadIdx.x;
    int lane = threadIdx.x & 63, wid = threadIdx.x >> 6;
    int v = (i < N_NODESC) ? deg[i] : 0;
    int incl = v;
    #pragma unroll
    for (int off = 1; off < 64; off <<= 1) {
        int n = __shfl_up(incl, off);
        if (lane >= off) incl += n;
    }
    if (lane == 63) wsum[wid] = incl;
    __syncthreads();
    int wpre = 0;
    #pragma unroll
    for (int w = 0; w < 4; w++) wpre += (w < wid) ? wsum[w] : 0;
    if (i < N_NODESC) {
        int excl = boff[blockIdx.x] + wpre + incl - v;
        row_start[i] = excl;
        cursor[i]    = excl;
        inv_deg[i]   = 1.0f / (float)max(v, 1);
    }
}

__global__ void k_fill(const int* __restrict__ ei, int* __restrict__ cursor,
                       int* __restrict__ csr) {
    int e = blockIdx.x * blockDim.x + threadIdx.x;
    if (e < N_EDGESC) {
        int d = ei[N_EDGESC + e];
        int pos = atomicAdd(&cursor[d], 1);
        csr[pos] = ei[e];
    }
}

// one wave per (dst node, 32-channel chunk); chunk = blockIdx.x & 7 -> XCD
// working set per chunk = 20000*32*4 = 2.56 MB < 4 MB per-XCD L2
__global__ void __launch_bounds__(256) k_agg1(
        const float4* __restrict__ x4,
        const int* __restrict__ row_start, const int* __restrict__ csr,
        const float* __restrict__ inv_deg, float4* __restrict__ mean4) {
    int wid   = threadIdx.x >> 6;
    int lane  = threadIdx.x & 63;
    int chunk = blockIdx.x & 7;
    int node  = (blockIdx.x >> 3) * 4 + wid;
    if (node >= N_NODESC) return;
    int c4 = lane & 7;             // float4 within the 32-ch chunk
    int eg = lane >> 3;            // edge subgroup 0..7
    int cbase = chunk * 8 + c4;
    int start = row_start[node], end = row_start[node + 1];
    float4 acc = make_float4(0, 0, 0, 0);
    int j = start;
    for (; j + 64 <= end; j += 64) {
        int idx = __builtin_nontemporal_load(&csr[j + lane]);
        #pragma unroll
        for (int k = 0; k < 8; k++) {
            int src = __shfl(idx, k * 8 + eg);
            acc = f4add(acc, x4[src * CH4 + cbase]);
        }
    }
    int rem = end - j;
    if (rem > 0) {
        int idx = (lane < rem) ? __builtin_nontemporal_load(&csr[j + lane]) : 0;
        #pragma unroll
        for (int k = 0; k < 8; k++) {
            int e = k * 8 + eg;
            int src = __shfl(idx, e);
            if (e < rem) acc = f4add(acc, x4[src * CH4 + cbase]);
        }
    }
    // reduce across the 8 edge subgroups (xor bits 3..5 of lane)
    #pragma unroll
    for (int off = 8; off < 64; off <<= 1) {
        acc.x += __shfl_xor(acc.x, off);
        acc.y += __shfl_xor(acc.y, off);
        acc.z += __shfl_xor(acc.z, off);
        acc.w += __shfl_xor(acc.w, off);
    }
    if (eg == 0) {
        float inv = inv_deg[node];
        mean4[node * CH4 + cbase] =
            make_float4(acc.x * inv, acc.y * inv, acc.z * inv, acc.w * inv);
    }
}

// h1 = relu([mean|x](20000x512) @ [W1_l|W1_r]^T(512x256) + b1)
// fused epilogue: s1[m] += h1[m,:].w2l ; t1[m] += h1[m,:].w2r  (h1 never stored)
// 64x64 tile, 256 threads, 4x4 per thread -> 313x4 = 1252 blocks (~5/CU)
#define BK 32
#define LDA 68
__global__ void __launch_bounds__(256) k_gemm1(
        const float4* __restrict__ mean4, const float4* __restrict__ x4,
        const float4* __restrict__ w1l4, const float4* __restrict__ w1r4,
        const float* __restrict__ b1, const float* __restrict__ w2l,
        const float* __restrict__ w2r,
        float* __restrict__ s1, float* __restrict__ t1) {
    __shared__ __align__(16) float As[BK][LDA];  // [k][m], 272B rows
    __shared__ __align__(16) float Bs[BK][LDA];  // [k][n]
    int tx = threadIdx.x & 15;   // n / 4
    int ty = threadIdx.x >> 4;   // m / 4  (0..15)
    int m0 = blockIdx.x * 64;
    int n0 = blockIdx.y * 64;
    float acc[4][4] = {};
    for (int kt = 0; kt < 16; kt++) {
        const float4* Abase = (kt < 8) ? mean4 : x4;
        const float4* Bbase = (kt < 8) ? w1l4  : w1r4;
        int kk0 = (kt & 7) * 8;  // float4 offset within 256-f row
        // stage A and B: 64 rows x 32 k each = 512 float4s each, 2/thread
        #pragma unroll
        for (int i = 0; i < 2; i++) {
            int f = threadIdx.x + i * 256;
            int row = f >> 3, c4 = f & 7;
            int m = m0 + row;
            float4 va = (m < N_NODESC) ? Abase[m * CH4 + kk0 + c4]
                                       : make_float4(0, 0, 0, 0);
            float4 vb = Bbase[(n0 + row) * CH4 + kk0 + c4];
            int k = c4 * 4;
            As[k + 0][row] = va.x; As[k + 1][row] = va.y;
            As[k + 2][row] = va.z; As[k + 3][row] = va.w;
            Bs[k + 0][row] = vb.x; Bs[k + 1][row] = vb.y;
            Bs[k + 2][row] = vb.z; Bs[k + 3][row] = vb.w;
        }
        __syncthreads();
        #pragma unroll
        for (int kk = 0; kk < BK; kk++) {
            float4 a0 = *(const float4*)&As[kk][ty * 4];
            float4 b0 = *(const float4*)&Bs[kk][tx * 4];
            float a[4] = {a0.x, a0.y, a0.z, a0.w};
            float b[4] = {b0.x, b0.y, b0.z, b0.w};
            #pragma unroll
            for (int i2 = 0; i2 < 4; i2++)
                #pragma unroll
                for (int j2 = 0; j2 < 4; j2++)
                    acc[i2][j2] += a[i2] * b[j2];
        }
        __syncthreads();
    }
    int nb = n0 + tx * 4;
    float bb0 = b1[nb + 0], bb1 = b1[nb + 1], bb2 = b1[nb + 2], bb3 = b1[nb + 3];
    float wl0 = w2l[nb + 0], wl1 = w2l[nb + 1], wl2 = w2l[nb + 2], wl3 = w2l[nb + 3];
    float wr0 = w2r[nb + 0], wr1 = w2r[nb + 1], wr2 = w2r[nb + 2], wr3 = w2r[nb + 3];
    #pragma unroll
    for (int i2 = 0; i2 < 4; i2++) {
        int m = m0 + ty * 4 + i2;
        float o0 = fmaxf(acc[i2][0] + bb0, 0.0f);
        float o1 = fmaxf(acc[i2][1] + bb1, 0.0f);
        float o2 = fmaxf(acc[i2][2] + bb2, 0.0f);
        float o3 = fmaxf(acc[i2][3] + bb3, 0.0f);
        float ps = o0 * wl0 + o1 * wl1 + o2 * wl2 + o3 * wl3;
        float pt = o0 * wr0 + o1 * wr1 + o2 * wr2 + o3 * wr3;
        #pragma unroll
        for (int off = 8; off > 0; off >>= 1) {
            ps += __shfl_down(ps, off, 16);
            pt += __shfl_down(pt, off, 16);
        }
        if (tx == 0 && m < N_NODESC) {
            atomicAdd(&s1[m], ps);
            atomicAdd(&t1[m], pt);
        }
    }
}

// per node: scalar segment-sum of s1 over in-edges, layer2 epilogue, fc dot
__global__ void __launch_bounds__(256) k_layer2(
        const int* __restrict__ row_start, const int* __restrict__ csr,
        const float* __restrict__ inv_deg, const float* __restrict__ s1,
        const float* __restrict__ t1, const float* __restrict__ b2,
        const float* __restrict__ fc_w, float* __restrict__ accum) {
    __shared__ float part[4];
    int wid = threadIdx.x >> 6, lane = threadIdx.x & 63;
    int node = blockIdx.x * 4 + wid;
    float contrib = 0.0f;
    if (node < N_NODESC) {
        int start = row_start[node], end = row_start[node + 1];
        float s = 0.0f;
        for (int j = start + lane; j < end; j += 64) s += s1[csr[j]];
        #pragma unroll
        for (int off = 32; off > 0; off >>= 1) s += __shfl_down(s, off);
        if (lane == 0) {
            float h2 = fmaxf(s * inv_deg[node] + b2[0] + t1[node], 0.0f);
            contrib = h2 * fc_w[node];
        }
    }
    if (lane == 0) part[wid] = contrib;
    __syncthreads();
    if (threadIdx.x == 0) {
        atomicAdd(accum, part[0] + part[1] + part[2] + part[3]);
    }
}

__global__ void k_final(const float* __restrict__ accum,
                        const float* __restrict__ fc_b, float* __restrict__ out) {
    out[0] = accum[0] + fc_b[0];
}

extern "C" void kernel_launch(void* const* d_in, const int* in_sizes, int n_in,
                              void* d_out, int out_size, void* d_ws, size_t ws_size,
                              hipStream_t stream) {
    const float* x    = (const float*)d_in[0];
    const int*   ei   = (const int*)d_in[1];
    const float* w1l  = (const float*)d_in[2];
    const float* b1   = (const float*)d_in[3];
    const float* w1r  = (const float*)d_in[4];
    const float* w2l  = (const float*)d_in[5];
    const float* b2   = (const float*)d_in[6];
    const float* w2r  = (const float*)d_in[7];
    const float* fcw  = (const float*)d_in[8];
    const float* fcb  = (const float*)d_in[9];
    float* out = (float*)d_out;

    char* ws = (char*)d_ws;
    int*   deg       = (int*)(ws + OFF_DEG);
    int*   row_start = (int*)(ws + OFF_ROWSTART);
    int*   cursor    = (int*)(ws + OFF_CURSOR);
    float* inv_deg   = (float*)(ws + OFF_INVDEG);
    float* accum     = (float*)(ws + OFF_ACCUM);
    int*   bsum      = (int*)(ws + OFF_BSUM);
    int*   boff      = (int*)(ws + OFF_BOFF);
    int*   csr       = (int*)(ws + OFF_CSR);
    float* meanb     = (float*)(ws + OFF_MEAN);
    float* s1        = (float*)(ws + OFF_S1);
    float* t1        = (float*)(ws + OFF_T1);

    k_zero<<<79, 256, 0, stream>>>(deg, s1, t1, accum);
    k_count<<<5000, 256, 0, stream>>>(ei, deg);
    k_scan1<<<79, 256, 0, stream>>>(deg, bsum);
    k_scan2<<<1, 128, 0, stream>>>(bsum, boff, row_start);
    k_scan3<<<79, 256, 0, stream>>>(deg, boff, row_start, cursor, inv_deg);
    k_fill<<<5000, 256, 0, stream>>>(ei, cursor, csr);
    k_agg1<<<40000, 256, 0, stream>>>((const float4*)x, row_start, csr, inv_deg,
                                      (float4*)meanb);
    dim3 ggrid(313, 4);
    k_gemm1<<<ggrid, 256, 0, stream>>>((const float4*)meanb, (const float4*)x,
                                       (const float4*)w1l, (const float4*)w1r,
                                       b1, w2l, w2r, s1, t1);
    k_layer2<<<5000, 256, 0, stream>>>(row_start, csr, inv_deg, s1, t1, b2,
                                       fcw, accum);
    k_final<<<1, 1, 0, stream>>>(accum, fcb, out);
}

// Round 4
// 313.307 us; speedup vs baseline: 1.5718x; 1.5718x over previous
//
#include <hip/hip_runtime.h>

#define N_NODESC 20000
#define N_EDGESC 1280000
#define NB 256          // csr-build blocks
#define EPB 5000        // edges per build block

typedef short bf16x8 __attribute__((ext_vector_type(8)));
typedef float f32x4 __attribute__((ext_vector_type(4)));

// ---- workspace layout (bytes, all 16B-aligned) ----
constexpr size_t OFF_DEG      = 0;          // int[20000]
constexpr size_t OFF_ROWSTART = 81920;      // int[20001]
constexpr size_t OFF_INVDEG   = 163840;     // float[20000]
constexpr size_t OFF_ACCUM    = 245760;     // float[4]
constexpr size_t OFF_BSUM     = 245776;     // int[128]
constexpr size_t OFF_BOFF     = 246288;     // int[128]
constexpr size_t OFF_S1       = 246800;     // float[20000]
constexpr size_t OFF_T1       = 326800;     // float[20000]
constexpr size_t OFF_HIST     = 406800;     // ushort[256][20000] = 10.24 MB
constexpr size_t OFF_CSR      = 10646800;   // int[1280000]
constexpr size_t OFF_XB       = 15766800;   // bf16[20000][256] = 10.24 MB
constexpr size_t OFF_MEANB    = 26006800;   // bf16[20000][256]
constexpr size_t OFF_W1LB     = 36246800;   // bf16[256][256]
constexpr size_t OFF_W1RB     = 36377872;   // bf16[256][256] (end ~36.5 MB)

static __device__ __forceinline__ unsigned f2bf(float f) {
    unsigned u = __float_as_uint(f);
    return ((u + 0x7fffu + ((u >> 16) & 1u)) >> 16) & 0xffffu;  // RTNE
}
static __device__ __forceinline__ float bflo(unsigned w) {
    return __uint_as_float(w << 16);
}
static __device__ __forceinline__ float bfhi(unsigned w) {
    return __uint_as_float(w & 0xffff0000u);
}

__global__ void k_zero(float* __restrict__ s1, float* __restrict__ t1,
                       float* __restrict__ accum) {
    int i = blockIdx.x * blockDim.x + threadIdx.x;
    if (i < N_NODESC) { s1[i] = 0.0f; t1[i] = 0.0f; }
    if (i == 0) accum[0] = 0.0f;
}

// cast x, W1_l, W1_r to bf16 (8 floats / thread)
__global__ void __launch_bounds__(256) k_cast(
        const float4* __restrict__ x, const float4* __restrict__ w1l,
        const float4* __restrict__ w1r, uint4* __restrict__ xb,
        uint4* __restrict__ w1lb, uint4* __restrict__ w1rb) {
    int g = blockIdx.x * 256 + threadIdx.x;   // 8-float group id
    const float4* src; uint4* dst; int off;
    if (g < 640000)      { src = x;   dst = xb;   off = g; }
    else if (g < 648192) { src = w1l; dst = w1lb; off = g - 640000; }
    else                 { src = w1r; dst = w1rb; off = g - 648192; }
    float4 a = src[off * 2], b = src[off * 2 + 1];
    uint4 o;
    o.x = f2bf(a.x) | (f2bf(a.y) << 16);
    o.y = f2bf(a.z) | (f2bf(a.w) << 16);
    o.z = f2bf(b.x) | (f2bf(b.y) << 16);
    o.w = f2bf(b.z) | (f2bf(b.w) << 16);
    dst[off] = o;
}

// per-block LDS histogram of dst (two 16-bit counters packed per word)
__global__ void __launch_bounds__(256) k_hist(const int* __restrict__ ei,
                                              unsigned short* __restrict__ hist) {
    __shared__ unsigned int lh[10000];
    int b = blockIdx.x, t = threadIdx.x;
    for (int w = t; w < 10000; w += 256) lh[w] = 0;
    __syncthreads();
    int base = b * EPB;
    for (int i = t; i < EPB; i += 256) {
        int d = ei[N_EDGESC + base + i];
        atomicAdd(&lh[d >> 1], (d & 1) ? 0x10000u : 1u);
    }
    __syncthreads();
    unsigned int* gh = (unsigned int*)(hist + (size_t)b * N_NODESC);
    for (int w = t; w < 10000; w += 256) gh[w] = lh[w];
}

// per bin: exclusive prefix across the 256 build blocks (4 waves x 64 blks),
// hist[blk][bin] <- prefix; deg[bin] <- total
__global__ void __launch_bounds__(256) k_prefix(unsigned short* __restrict__ hist,
                                                int* __restrict__ deg) {
    __shared__ int wtot[4][64];
    int t = threadIdx.x;
    int lb = t & 63, sub = t >> 6;
    int bin = blockIdx.x * 64 + lb;
    bool ok = bin < N_NODESC;
    int run = 0;
    if (ok) {
        for (int i = 0; i < 64; i++)
            run += hist[(size_t)(sub * 64 + i) * N_NODESC + bin];
    }
    wtot[sub][lb] = run;
    __syncthreads();
    int off = 0, total = 0;
    for (int w = 0; w < 4; w++) {
        int v = wtot[w][lb];
        if (w < sub) off += v;
        total += v;
    }
    if (ok) {
        if (sub == 0) deg[bin] = total;
        int run2 = off;
        for (int i = 0; i < 64; i++) {
            size_t idx = (size_t)(sub * 64 + i) * N_NODESC + bin;
            int v = hist[idx];
            hist[idx] = (unsigned short)run2;
            run2 += v;
        }
    }
}

// --- 3-phase scan of deg -> row_start, inv_deg ---
__global__ void __launch_bounds__(256) k_scan1(const int* __restrict__ deg,
                                               int* __restrict__ bsum) {
    __shared__ int sm[4];
    int i = blockIdx.x * 256 + threadIdx.x;
    int v = (i < N_NODESC) ? deg[i] : 0;
    #pragma unroll
    for (int off = 32; off > 0; off >>= 1) v += __shfl_down(v, off);
    if ((threadIdx.x & 63) == 0) sm[threadIdx.x >> 6] = v;
    __syncthreads();
    if (threadIdx.x == 0) bsum[blockIdx.x] = sm[0] + sm[1] + sm[2] + sm[3];
}

__global__ void k_scan2(const int* __restrict__ bsum, int* __restrict__ boff,
                        int* __restrict__ row_start) {
    __shared__ int sm[128];
    int t = threadIdx.x;
    int v = (t < 79) ? bsum[t] : 0;
    sm[t] = v;
    __syncthreads();
    for (int off = 1; off < 128; off <<= 1) {
        int add = (t >= off) ? sm[t - off] : 0;
        __syncthreads();
        sm[t] += add;
        __syncthreads();
    }
    if (t < 79) boff[t] = sm[t] - v;
    if (t == 0) row_start[N_NODESC] = sm[127];
}

__global__ void __launch_bounds__(256) k_scan3(
        const int* __restrict__ deg, const int* __restrict__ boff,
        int* __restrict__ row_start, float* __restrict__ inv_deg) {
    __shared__ int wsum[4];
    int i = blockIdx.x * 256 + threadIdx.x;
    int lane = threadIdx.x & 63, wid = threadIdx.x >> 6;
    int v = (i < N_NODESC) ? deg[i] : 0;
    int incl = v;
    #pragma unroll
    for (int off = 1; off < 64; off <<= 1) {
        int n = __shfl_up(incl, off);
        if (lane >= off) incl += n;
    }
    if (lane == 63) wsum[wid] = incl;
    __syncthreads();
    int wpre = 0;
    #pragma unroll
    for (int w = 0; w < 4; w++) wpre += (w < wid) ? wsum[w] : 0;
    if (i < N_NODESC) {
        row_start[i] = boff[blockIdx.x] + wpre + incl - v;
        inv_deg[i]   = 1.0f / (float)max(v, 1);
    }
}

// scatter edges into CSR: rank via LDS atomics, base via hist prefix
__global__ void __launch_bounds__(256) k_fill2(const int* __restrict__ ei,
        const int* __restrict__ row_start, const unsigned short* __restrict__ hist,
        int* __restrict__ csr) {
    __shared__ unsigned int lh[10000];
    int b = blockIdx.x, t = threadIdx.x;
    for (int w = t; w < 10000; w += 256) lh[w] = 0;
    __syncthreads();
    int base = b * EPB;
    const unsigned short* hb = hist + (size_t)b * N_NODESC;
    for (int i = t; i < EPB; i += 256) {
        int e = base + i;
        int d = ei[N_EDGESC + e];
        int s = ei[e];
        unsigned int old = atomicAdd(&lh[d >> 1], (d & 1) ? 0x10000u : 1u);
        int rank = (d & 1) ? (int)(old >> 16) : (int)(old & 0xffffu);
        int pos = row_start[d] + (int)hb[d] + rank;
        csr[pos] = s;
    }
}

// one wave per (dst node, 64-ch chunk), bf16 rows: 128B = 1 line per edge-chunk
// per-chunk working set = 20000*64*2 = 2.56 MB < 4 MB per-XCD L2
__global__ void __launch_bounds__(256) k_agg(const uint4* __restrict__ xb4,
        const int* __restrict__ row_start, const int* __restrict__ csr,
        const float* __restrict__ inv_deg, uint4* __restrict__ meanb4) {
    int wid = threadIdx.x >> 6, lane = threadIdx.x & 63;
    int chunk = blockIdx.x & 3;
    int node = (blockIdx.x >> 2) * 4 + wid;
    int c = lane & 7, eg = lane >> 3;
    int cb = chunk * 8 + c;
    int start = row_start[node], end = row_start[node + 1];
    float a0=0,a1=0,a2=0,a3=0,a4=0,a5=0,a6=0,a7=0;
    int j = start;
    for (; j + 64 <= end; j += 64) {
        int idx = __builtin_nontemporal_load(&csr[j + lane]);
        #pragma unroll
        for (int k = 0; k < 8; k++) {
            int src = __shfl(idx, k * 8 + eg);
            uint4 v = xb4[(size_t)src * 32 + cb];
            a0 += bflo(v.x); a1 += bfhi(v.x);
            a2 += bflo(v.y); a3 += bfhi(v.y);
            a4 += bflo(v.z); a5 += bfhi(v.z);
            a6 += bflo(v.w); a7 += bfhi(v.w);
        }
    }
    int rem = end - j;
    if (rem > 0) {
        int idx = (lane < rem) ? __builtin_nontemporal_load(&csr[j + lane]) : 0;
        #pragma unroll
        for (int k = 0; k < 8; k++) {
            int e = k * 8 + eg;
            int src = __shfl(idx, e);
            if (e < rem) {
                uint4 v = xb4[(size_t)src * 32 + cb];
                a0 += bflo(v.x); a1 += bfhi(v.x);
                a2 += bflo(v.y); a3 += bfhi(v.y);
                a4 += bflo(v.z); a5 += bfhi(v.z);
                a6 += bflo(v.w); a7 += bfhi(v.w);
            }
        }
    }
    #pragma unroll
    for (int off = 8; off < 64; off <<= 1) {
        a0 += __shfl_xor(a0, off); a1 += __shfl_xor(a1, off);
        a2 += __shfl_xor(a2, off); a3 += __shfl_xor(a3, off);
        a4 += __shfl_xor(a4, off); a5 += __shfl_xor(a5, off);
        a6 += __shfl_xor(a6, off); a7 += __shfl_xor(a7, off);
    }
    if (eg == 0) {
        float inv = inv_deg[node];
        uint4 o;
        o.x = f2bf(a0 * inv) | (f2bf(a1 * inv) << 16);
        o.y = f2bf(a2 * inv) | (f2bf(a3 * inv) << 16);
        o.z = f2bf(a4 * inv) | (f2bf(a5 * inv) << 16);
        o.w = f2bf(a6 * inv) | (f2bf(a7 * inv) << 16);
        meanb4[(size_t)node * 32 + cb] = o;
    }
}

// h1 = relu([mean|x] @ [W1l|W1r]^T + b1) via bf16 MFMA (fp32 accum), fused
// epilogue s1 += h1.w2l, t1 += h1.w2r. 64x64 tile, BK=64, 4 waves.
// A-frag: lane holds A[m=l&15][k=(l>>4)*8+j]; B-frag: B[k=(l>>4)*8+j][n=l&15];
// C/D: col=l&15, row=(l>>4)*4+reg  [m89/m91/m120]
__global__ void __launch_bounds__(256) k_gemm(const uint4* __restrict__ meanb4,
        const uint4* __restrict__ xb4, const uint4* __restrict__ w1lb4,
        const uint4* __restrict__ w1rb4, const float* __restrict__ b1,
        const float* __restrict__ w2l, const float* __restrict__ w2r,
        float* __restrict__ s1, float* __restrict__ t1) {
    __shared__ __align__(16) unsigned short As[64][72];
    __shared__ __align__(16) unsigned short Bs[64][72];
    int t = threadIdx.x;
    int m0 = blockIdx.x * 64, n0 = blockIdx.y * 64;
    int wv = t >> 6, l = t & 63, lr = l & 15, quad = l >> 4;
    f32x4 acc[4] = {{0,0,0,0},{0,0,0,0},{0,0,0,0},{0,0,0,0}};
    for (int kt = 0; kt < 8; kt++) {
        const uint4* Asrc = (kt < 4) ? meanb4 : xb4;
        const uint4* Bsrc = (kt < 4) ? w1lb4 : w1rb4;
        int k0q = (kt & 3) * 8;
        #pragma unroll
        for (int p = 0; p < 2; p++) {
            int f = t + p * 256;
            int row = f >> 3, cc = f & 7;
            int m = m0 + row;
            uint4 va = (m < N_NODESC) ? Asrc[(size_t)m * 32 + k0q + cc]
                                      : make_uint4(0, 0, 0, 0);
            uint4 vb = Bsrc[(size_t)(n0 + row) * 32 + k0q + cc];
            *(uint4*)&As[row][cc * 8] = va;
            *(uint4*)&Bs[row][cc * 8] = vb;
        }
        __syncthreads();
        #pragma unroll
        for (int ks = 0; ks < 64; ks += 32) {
            bf16x8 af = *(const bf16x8*)&As[wv * 16 + lr][ks + quad * 8];
            #pragma unroll
            for (int jj = 0; jj < 4; jj++) {
                bf16x8 bf = *(const bf16x8*)&Bs[jj * 16 + lr][ks + quad * 8];
                acc[jj] = __builtin_amdgcn_mfma_f32_16x16x32_bf16(
                              af, bf, acc[jj], 0, 0, 0);
            }
        }
        __syncthreads();
    }
    float ps[4] = {0, 0, 0, 0}, pt[4] = {0, 0, 0, 0};
    #pragma unroll
    for (int jj = 0; jj < 4; jj++) {
        int col = n0 + jj * 16 + lr;
        float bb = b1[col], wl = w2l[col], wr = w2r[col];
        #pragma unroll
        for (int r = 0; r < 4; r++) {
            float h = fmaxf(acc[jj][r] + bb, 0.0f);
            ps[r] += h * wl; pt[r] += h * wr;
        }
    }
    #pragma unroll
    for (int r = 0; r < 4; r++) {
        #pragma unroll
        for (int off = 8; off > 0; off >>= 1) {
            ps[r] += __shfl_down(ps[r], off, 16);
            pt[r] += __shfl_down(pt[r], off, 16);
        }
    }
    if (lr == 0) {
        int mb = m0 + wv * 16 + quad * 4;
        #pragma unroll
        for (int r = 0; r < 4; r++) {
            int m = mb + r;
            if (m < N_NODESC) {
                atomicAdd(&s1[m], ps[r]);
                atomicAdd(&t1[m], pt[r]);
            }
        }
    }
}

// layer-2 scalar aggregation + epilogue + fc dot
__global__ void __launch_bounds__(256) k_layer2(
        const int* __restrict__ row_start, const int* __restrict__ csr,
        const float* __restrict__ inv_deg, const float* __restrict__ s1,
        const float* __restrict__ t1, const float* __restrict__ b2,
        const float* __restrict__ fc_w, float* __restrict__ accum) {
    __shared__ float part[4];
    int wid = threadIdx.x >> 6, lane = threadIdx.x & 63;
    int node = blockIdx.x * 4 + wid;
    float contrib = 0.0f;
    if (node < N_NODESC) {
        int start = row_start[node], end = row_start[node + 1];
        float s = 0.0f;
        for (int j = start + lane; j < end; j += 64) s += s1[csr[j]];
        #pragma unroll
        for (int off = 32; off > 0; off >>= 1) s += __shfl_down(s, off);
        if (lane == 0) {
            float h2 = fmaxf(s * inv_deg[node] + b2[0] + t1[node], 0.0f);
            contrib = h2 * fc_w[node];
        }
    }
    if (lane == 0) part[wid] = contrib;
    __syncthreads();
    if (threadIdx.x == 0)
        atomicAdd(accum, part[0] + part[1] + part[2] + part[3]);
}

__global__ void k_final(const float* __restrict__ accum,
                        const float* __restrict__ fc_b, float* __restrict__ out) {
    out[0] = accum[0] + fc_b[0];
}

extern "C" void kernel_launch(void* const* d_in, const int* in_sizes, int n_in,
                              void* d_out, int out_size, void* d_ws, size_t ws_size,
                              hipStream_t stream) {
    const float* x    = (const float*)d_in[0];
    const int*   ei   = (const int*)d_in[1];
    const float* w1l  = (const float*)d_in[2];
    const float* b1   = (const float*)d_in[3];
    const float* w1r  = (const float*)d_in[4];
    const float* w2l  = (const float*)d_in[5];
    const float* b2   = (const float*)d_in[6];
    const float* w2r  = (const float*)d_in[7];
    const float* fcw  = (const float*)d_in[8];
    const float* fcb  = (const float*)d_in[9];
    float* out = (float*)d_out;

    char* ws = (char*)d_ws;
    int*    deg       = (int*)(ws + OFF_DEG);
    int*    row_start = (int*)(ws + OFF_ROWSTART);
    float*  inv_deg   = (float*)(ws + OFF_INVDEG);
    float*  accum     = (float*)(ws + OFF_ACCUM);
    int*    bsum      = (int*)(ws + OFF_BSUM);
    int*    boff      = (int*)(ws + OFF_BOFF);
    float*  s1        = (float*)(ws + OFF_S1);
    float*  t1        = (float*)(ws + OFF_T1);
    unsigned short* hist = (unsigned short*)(ws + OFF_HIST);
    int*    csr       = (int*)(ws + OFF_CSR);
    uint4*  xb4       = (uint4*)(ws + OFF_XB);
    uint4*  meanb4    = (uint4*)(ws + OFF_MEANB);
    uint4*  w1lb4     = (uint4*)(ws + OFF_W1LB);
    uint4*  w1rb4     = (uint4*)(ws + OFF_W1RB);

    k_zero<<<79, 256, 0, stream>>>(s1, t1, accum);
    k_cast<<<2564, 256, 0, stream>>>((const float4*)x, (const float4*)w1l,
                                     (const float4*)w1r, xb4, w1lb4, w1rb4);
    k_hist<<<NB, 256, 0, stream>>>(ei, hist);
    k_prefix<<<313, 256, 0, stream>>>(hist, deg);
    k_scan1<<<79, 256, 0, stream>>>(deg, bsum);
    k_scan2<<<1, 128, 0, stream>>>(bsum, boff, row_start);
    k_scan3<<<79, 256, 0, stream>>>(deg, boff, row_start, inv_deg);
    k_fill2<<<NB, 256, 0, stream>>>(ei, row_start, hist, csr);
    k_agg<<<20000, 256, 0, stream>>>((const uint4*)xb4, row_start, csr, inv_deg,
                                     meanb4);
    dim3 ggrid(313, 4);
    k_gemm<<<ggrid, 256, 0, stream>>>((const uint4*)meanb4, (const uint4*)xb4,
                                      (const uint4*)w1lb4, (const uint4*)w1rb4,
                                      b1, w2l, w2r, s1, t1);
    k_layer2<<<5000, 256, 0, stream>>>(row_start, csr, inv_deg, s1, t1, b2,
                                       fcw, accum);
    k_final<<<1, 1, 0, stream>>>(accum, fcb, out);
}

// Round 5
// 303.854 us; speedup vs baseline: 1.6207x; 1.0311x over previous
//
#include <hip/hip_runtime.h>

#define N_NODESC 20000
#define N_EDGESC 1280000
#define NB 256          // csr-build blocks
#define EPB 5000        // edges per build block

typedef short bf16x8 __attribute__((ext_vector_type(8)));
typedef float f32x4 __attribute__((ext_vector_type(4)));

// ---- workspace layout (bytes, all 16B-aligned) ----
constexpr size_t OFF_DEG      = 0;          // int[20000]
constexpr size_t OFF_ROWSTART = 81920;      // int[20001]
constexpr size_t OFF_INVDEG   = 163840;     // float[20000]
constexpr size_t OFF_ACCUM    = 245760;     // float[4]
constexpr size_t OFF_BSUM     = 245776;     // int[128]
constexpr size_t OFF_BOFF     = 246288;     // int[128]
constexpr size_t OFF_S1       = 246800;     // float[20000]
constexpr size_t OFF_T1       = 326800;     // float[20000]
constexpr size_t OFF_HIST     = 406800;     // ushort[256][20000] = 10.24 MB
constexpr size_t OFF_CSR      = 10646800;   // int[1280000] (+64 pad ok: next region read-only)
constexpr size_t OFF_XB       = 15766800;   // bf16[20000][256] = 10.24 MB
constexpr size_t OFF_MEANB    = 26006800;   // bf16[20000][256]
constexpr size_t OFF_W1LB     = 36246800;   // bf16[256][256]
constexpr size_t OFF_W1RB     = 36377872;   // bf16[256][256] (end ~36.5 MB)

static __device__ __forceinline__ unsigned f2bf(float f) {
    unsigned u = __float_as_uint(f);
    return ((u + 0x7fffu + ((u >> 16) & 1u)) >> 16) & 0xffffu;  // RTNE
}
static __device__ __forceinline__ float bflo(unsigned w) {
    return __uint_as_float(w << 16);
}
static __device__ __forceinline__ float bfhi(unsigned w) {
    return __uint_as_float(w & 0xffff0000u);
}

__global__ void k_zero(float* __restrict__ s1, float* __restrict__ t1,
                       float* __restrict__ accum, int* __restrict__ bsum) {
    int i = blockIdx.x * blockDim.x + threadIdx.x;
    if (i < N_NODESC) { s1[i] = 0.0f; t1[i] = 0.0f; }
    if (i < 128) bsum[i] = 0;
    if (i == 0) accum[0] = 0.0f;
}

// cast x, W1_l, W1_r to bf16 (8 floats / thread)
__global__ void __launch_bounds__(256) k_cast(
        const float4* __restrict__ x, const float4* __restrict__ w1l,
        const float4* __restrict__ w1r, uint4* __restrict__ xb,
        uint4* __restrict__ w1lb, uint4* __restrict__ w1rb) {
    int g = blockIdx.x * 256 + threadIdx.x;   // 8-float group id
    const float4* src; uint4* dst; int off;
    if (g < 640000)      { src = x;   dst = xb;   off = g; }
    else if (g < 648192) { src = w1l; dst = w1lb; off = g - 640000; }
    else                 { src = w1r; dst = w1rb; off = g - 648192; }
    float4 a = src[off * 2], b = src[off * 2 + 1];
    uint4 o;
    o.x = f2bf(a.x) | (f2bf(a.y) << 16);
    o.y = f2bf(a.z) | (f2bf(a.w) << 16);
    o.z = f2bf(b.x) | (f2bf(b.y) << 16);
    o.w = f2bf(b.z) | (f2bf(b.w) << 16);
    dst[off] = o;
}

// per-block LDS histogram of dst (two 16-bit counters packed per word)
__global__ void __launch_bounds__(256) k_hist(const int* __restrict__ ei,
                                              unsigned short* __restrict__ hist) {
    __shared__ unsigned int lh[10000];
    int b = blockIdx.x, t = threadIdx.x;
    for (int w = t; w < 10000; w += 256) lh[w] = 0;
    __syncthreads();
    int base = b * EPB;
    for (int i = t; i < EPB; i += 256) {
        int d = ei[N_EDGESC + base + i];
        atomicAdd(&lh[d >> 1], (d & 1) ? 0x10000u : 1u);
    }
    __syncthreads();
    unsigned int* gh = (unsigned int*)(hist + (size_t)b * N_NODESC);
    for (int w = t; w < 10000; w += 256) gh[w] = lh[w];
}

// per bin: exclusive prefix across the 256 build blocks (4 waves x 64 blks),
// hist[blk][bin] <- prefix; deg[bin] <- total; bsum[bin>>8] += total (scan1 fused)
__global__ void __launch_bounds__(256) k_prefix(unsigned short* __restrict__ hist,
                                                int* __restrict__ deg,
                                                int* __restrict__ bsum) {
    __shared__ int wtot[4][64];
    int t = threadIdx.x;
    int lb = t & 63, sub = t >> 6;
    int bin = blockIdx.x * 64 + lb;
    bool ok = bin < N_NODESC;
    int run = 0;
    if (ok) {
        for (int i = 0; i < 64; i++)
            run += hist[(size_t)(sub * 64 + i) * N_NODESC + bin];
    }
    wtot[sub][lb] = run;
    __syncthreads();
    int off = 0, total = 0;
    for (int w = 0; w < 4; w++) {
        int v = wtot[w][lb];
        if (w < sub) off += v;
        total += v;
    }
    if (sub == 0) {
        int tv = ok ? total : 0;
        if (ok) deg[bin] = total;
        #pragma unroll
        for (int o2 = 32; o2 > 0; o2 >>= 1) tv += __shfl_down(tv, o2);
        if (lb == 0) atomicAdd(&bsum[(blockIdx.x * 64) >> 8], tv);
    }
    if (ok) {
        int run2 = off;
        for (int i = 0; i < 64; i++) {
            size_t idx = (size_t)(sub * 64 + i) * N_NODESC + bin;
            int v = hist[idx];
            hist[idx] = (unsigned short)run2;
            run2 += v;
        }
    }
}

__global__ void k_scan2(const int* __restrict__ bsum, int* __restrict__ boff,
                        int* __restrict__ row_start) {
    __shared__ int sm[128];
    int t = threadIdx.x;
    int v = (t < 79) ? bsum[t] : 0;
    sm[t] = v;
    __syncthreads();
    for (int off = 1; off < 128; off <<= 1) {
        int add = (t >= off) ? sm[t - off] : 0;
        __syncthreads();
        sm[t] += add;
        __syncthreads();
    }
    if (t < 79) boff[t] = sm[t] - v;
    if (t == 0) row_start[N_NODESC] = sm[127];
}

__global__ void __launch_bounds__(256) k_scan3(
        const int* __restrict__ deg, const int* __restrict__ boff,
        int* __restrict__ row_start, float* __restrict__ inv_deg) {
    __shared__ int wsum[4];
    int i = blockIdx.x * 256 + threadIdx.x;
    int lane = threadIdx.x & 63, wid = threadIdx.x >> 6;
    int v = (i < N_NODESC) ? deg[i] : 0;
    int incl = v;
    #pragma unroll
    for (int off = 1; off < 64; off <<= 1) {
        int n = __shfl_up(incl, off);
        if (lane >= off) incl += n;
    }
    if (lane == 63) wsum[wid] = incl;
    __syncthreads();
    int wpre = 0;
    #pragma unroll
    for (int w = 0; w < 4; w++) wpre += (w < wid) ? wsum[w] : 0;
    if (i < N_NODESC) {
        row_start[i] = boff[blockIdx.x] + wpre + incl - v;
        inv_deg[i]   = 1.0f / (float)max(v, 1);
    }
}

// scatter edges into CSR: rank via LDS atomics, base via hist prefix
__global__ void __launch_bounds__(256) k_fill2(const int* __restrict__ ei,
        const int* __restrict__ row_start, const unsigned short* __restrict__ hist,
        int* __restrict__ csr) {
    __shared__ unsigned int lh[10000];
    int b = blockIdx.x, t = threadIdx.x;
    for (int w = t; w < 10000; w += 256) lh[w] = 0;
    __syncthreads();
    int base = b * EPB;
    const unsigned short* hb = hist + (size_t)b * N_NODESC;
    for (int i = t; i < EPB; i += 256) {
        int e = base + i;
        int d = ei[N_EDGESC + e];
        int s = ei[e];
        unsigned int old = atomicAdd(&lh[d >> 1], (d & 1) ? 0x10000u : 1u);
        int rank = (d & 1) ? (int)(old >> 16) : (int)(old & 0xffffu);
        int pos = row_start[d] + (int)hb[d] + rank;
        csr[pos] = s;
    }
}

// one wave per node, lane owns 4 bf16 channels (8B). Edge index made
// wave-uniform via readlane -> gather is uniform-SGPR-base + invariant lane
// offset (scalar-pipe address math, no shfl, no per-lane addressing, and no
// cross-lane reduction at the end).
__global__ void __launch_bounds__(256) k_agg(const uint2* __restrict__ xb2,
        const int* __restrict__ row_start, const int* __restrict__ csr,
        const float* __restrict__ inv_deg, uint2* __restrict__ meanb2) {
    int wid = threadIdx.x >> 6, lane = threadIdx.x & 63;
    int node = blockIdx.x * 4 + wid;
    int start = row_start[node], end = row_start[node + 1];
    float a0 = 0.f, a1 = 0.f, a2 = 0.f, a3 = 0.f;
    for (int j = start; j < end; j += 64) {
        int cnt = min(64, end - j);
        int idx = csr[j + lane];           // ok to over-read <=63 (in ws)
        int k = 0;
        for (; k + 8 <= cnt; k += 8) {
            #pragma unroll
            for (int u = 0; u < 8; u++) {
                int src = __builtin_amdgcn_readlane(idx, k + u);
                uint2 v = xb2[(size_t)src * 64 + lane];
                a0 += bflo(v.x); a1 += bfhi(v.x);
                a2 += bflo(v.y); a3 += bfhi(v.y);
            }
        }
        for (; k < cnt; k++) {
            int src = __builtin_amdgcn_readlane(idx, k);
            uint2 v = xb2[(size_t)src * 64 + lane];
            a0 += bflo(v.x); a1 += bfhi(v.x);
            a2 += bflo(v.y); a3 += bfhi(v.y);
        }
    }
    float inv = inv_deg[node];
    uint2 o;
    o.x = f2bf(a0 * inv) | (f2bf(a1 * inv) << 16);
    o.y = f2bf(a2 * inv) | (f2bf(a3 * inv) << 16);
    meanb2[(size_t)node * 64 + lane] = o;
}

// h1 = relu([mean|x] @ [W1l|W1r]^T + b1) via bf16 MFMA (fp32 accum), fused
// epilogue s1 += h1.w2l, t1 += h1.w2r. 64x64 tile, BK=64, 4 waves.
__global__ void __launch_bounds__(256) k_gemm(const uint4* __restrict__ meanb4,
        const uint4* __restrict__ xb4, const uint4* __restrict__ w1lb4,
        const uint4* __restrict__ w1rb4, const float* __restrict__ b1,
        const float* __restrict__ w2l, const float* __restrict__ w2r,
        float* __restrict__ s1, float* __restrict__ t1) {
    __shared__ __align__(16) unsigned short As[64][72];
    __shared__ __align__(16) unsigned short Bs[64][72];
    int t = threadIdx.x;
    int m0 = blockIdx.x * 64, n0 = blockIdx.y * 64;
    int wv = t >> 6, l = t & 63, lr = l & 15, quad = l >> 4;
    f32x4 acc[4] = {{0,0,0,0},{0,0,0,0},{0,0,0,0},{0,0,0,0}};
    for (int kt = 0; kt < 8; kt++) {
        const uint4* Asrc = (kt < 4) ? meanb4 : xb4;
        const uint4* Bsrc = (kt < 4) ? w1lb4 : w1rb4;
        int k0q = (kt & 3) * 8;
        #pragma unroll
        for (int p = 0; p < 2; p++) {
            int f = t + p * 256;
            int row = f >> 3, cc = f & 7;
            int m = m0 + row;
            uint4 va = (m < N_NODESC) ? Asrc[(size_t)m * 32 + k0q + cc]
                                      : make_uint4(0, 0, 0, 0);
            uint4 vb = Bsrc[(size_t)(n0 + row) * 32 + k0q + cc];
            *(uint4*)&As[row][cc * 8] = va;
            *(uint4*)&Bs[row][cc * 8] = vb;
        }
        __syncthreads();
        #pragma unroll
        for (int ks = 0; ks < 64; ks += 32) {
            bf16x8 af = *(const bf16x8*)&As[wv * 16 + lr][ks + quad * 8];
            #pragma unroll
            for (int jj = 0; jj < 4; jj++) {
                bf16x8 bf = *(const bf16x8*)&Bs[jj * 16 + lr][ks + quad * 8];
                acc[jj] = __builtin_amdgcn_mfma_f32_16x16x32_bf16(
                              af, bf, acc[jj], 0, 0, 0);
            }
        }
        __syncthreads();
    }
    float ps[4] = {0, 0, 0, 0}, pt[4] = {0, 0, 0, 0};
    #pragma unroll
    for (int jj = 0; jj < 4; jj++) {
        int col = n0 + jj * 16 + lr;
        float bb = b1[col], wl = w2l[col], wr = w2r[col];
        #pragma unroll
        for (int r = 0; r < 4; r++) {
            float h = fmaxf(acc[jj][r] + bb, 0.0f);
            ps[r] += h * wl; pt[r] += h * wr;
        }
    }
    #pragma unroll
    for (int r = 0; r < 4; r++) {
        #pragma unroll
        for (int off = 8; off > 0; off >>= 1) {
            ps[r] += __shfl_down(ps[r], off, 16);
            pt[r] += __shfl_down(pt[r], off, 16);
        }
    }
    if (lr == 0) {
        int mb = m0 + wv * 16 + quad * 4;
        #pragma unroll
        for (int r = 0; r < 4; r++) {
            int m = mb + r;
            if (m < N_NODESC) {
                atomicAdd(&s1[m], ps[r]);
                atomicAdd(&t1[m], pt[r]);
            }
        }
    }
}

// layer-2 scalar aggregation + epilogue + fc dot
__global__ void __launch_bounds__(256) k_layer2(
        const int* __restrict__ row_start, const int* __restrict__ csr,
        const float* __restrict__ inv_deg, const float* __restrict__ s1,
        const float* __restrict__ t1, const float* __restrict__ b2,
        const float* __restrict__ fc_w, float* __restrict__ accum) {
    __shared__ float part[4];
    int wid = threadIdx.x >> 6, lane = threadIdx.x & 63;
    int node = blockIdx.x * 4 + wid;
    float contrib = 0.0f;
    if (node < N_NODESC) {
        int start = row_start[node], end = row_start[node + 1];
        float s = 0.0f;
        for (int j = start + lane; j < end; j += 64) s += s1[csr[j]];
        #pragma unroll
        for (int off = 32; off > 0; off >>= 1) s += __shfl_down(s, off);
        if (lane == 0) {
            float h2 = fmaxf(s * inv_deg[node] + b2[0] + t1[node], 0.0f);
            contrib = h2 * fc_w[node];
        }
    }
    if (lane == 0) part[wid] = contrib;
    __syncthreads();
    if (threadIdx.x == 0)
        atomicAdd(accum, part[0] + part[1] + part[2] + part[3]);
}

__global__ void k_final(const float* __restrict__ accum,
                        const float* __restrict__ fc_b, float* __restrict__ out) {
    out[0] = accum[0] + fc_b[0];
}

extern "C" void kernel_launch(void* const* d_in, const int* in_sizes, int n_in,
                              void* d_out, int out_size, void* d_ws, size_t ws_size,
                              hipStream_t stream) {
    const float* x    = (const float*)d_in[0];
    const int*   ei   = (const int*)d_in[1];
    const float* w1l  = (const float*)d_in[2];
    const float* b1   = (const float*)d_in[3];
    const float* w1r  = (const float*)d_in[4];
    const float* w2l  = (const float*)d_in[5];
    const float* b2   = (const float*)d_in[6];
    const float* w2r  = (const float*)d_in[7];
    const float* fcw  = (const float*)d_in[8];
    const float* fcb  = (const float*)d_in[9];
    float* out = (float*)d_out;

    char* ws = (char*)d_ws;
    int*    deg       = (int*)(ws + OFF_DEG);
    int*    row_start = (int*)(ws + OFF_ROWSTART);
    float*  inv_deg   = (float*)(ws + OFF_INVDEG);
    float*  accum     = (float*)(ws + OFF_ACCUM);
    int*    bsum      = (int*)(ws + OFF_BSUM);
    int*    boff      = (int*)(ws + OFF_BOFF);
    float*  s1        = (float*)(ws + OFF_S1);
    float*  t1        = (float*)(ws + OFF_T1);
    unsigned short* hist = (unsigned short*)(ws + OFF_HIST);
    int*    csr       = (int*)(ws + OFF_CSR);
    uint2*  xb2       = (uint2*)(ws + OFF_XB);
    uint2*  meanb2    = (uint2*)(ws + OFF_MEANB);
    uint4*  w1lb4     = (uint4*)(ws + OFF_W1LB);
    uint4*  w1rb4     = (uint4*)(ws + OFF_W1RB);

    k_zero<<<79, 256, 0, stream>>>(s1, t1, accum, bsum);
    k_cast<<<2564, 256, 0, stream>>>((const float4*)x, (const float4*)w1l,
                                     (const float4*)w1r, (uint4*)xb2,
                                     w1lb4, w1rb4);
    k_hist<<<NB, 256, 0, stream>>>(ei, hist);
    k_prefix<<<313, 256, 0, stream>>>(hist, deg, bsum);
    k_scan2<<<1, 128, 0, stream>>>(bsum, boff, row_start);
    k_scan3<<<79, 256, 0, stream>>>(deg, boff, row_start, inv_deg);
    k_fill2<<<NB, 256, 0, stream>>>(ei, row_start, hist, csr);
    k_agg<<<5000, 256, 0, stream>>>((const uint2*)xb2, row_start, csr, inv_deg,
                                    meanb2);
    dim3 ggrid(313, 4);
    k_gemm<<<ggrid, 256, 0, stream>>>((const uint4*)meanb2, (const uint4*)xb2,
                                      (const uint4*)w1lb4, (const uint4*)w1rb4,
                                      b1, w2l, w2r, s1, t1);
    k_layer2<<<5000, 256, 0, stream>>>(row_start, csr, inv_deg, s1, t1, b2,
                                       fcw, accum);
    k_final<<<1, 1, 0, stream>>>(accum, fcb, out);
}